// Round 6
// baseline (149.085 us; speedup 1.0000x reference)
//
#include <hip/hip_runtime.h>

// Batched CBF-QP dual FISTA — r15: r13 structure (300 iters), half_step
// re-scheduled to fill reduce-phase latency bubbles.
// r14 post-mortem: N_FISTA=200 FAILED (absmax 5.84) — the reference's own
// trajectory moves ~5.8 between iters 200 and 300 for tail problems; 1/k^2
// fit says even 290 is borderline. Iteration count locked at 300.
// r13 post-mortem: busy 69% at 1 wave/SIMD — idle concentrated where width
// collapses (tree->DPP->X0/X1, DPP producer hazards). r15 hoists every op
// that does NOT depend on this iteration's reduces to the half_step top:
//   - NBZ[k] = NB[k] + ZV[k]  (resid chain ends in NBZ; 6 early adds)
//   - inner0/1 = fma(nsh*c, zC, u)  (X0 = fma(nsh, a0vec, inner0): depth 1)
//   - xC, ncbxz, and the whole slack2 row (prev-iter state only)
// Same op count (~90/half_step), ~16 ops relocated into the stall window.
// Algebra identical up to fp reassociation (ulp-level; budget 0.35 vs 0.03).
//
// Structure (unchanged): each thread owns TWO problems (A at q, B at q+half);
// every v2f holds {A,B} — v_pk_fma_f32 advances both chains in lockstep
// (r12 lesson: scheduler serializes separate chains; packing is structural).
//   - 4 lanes/quad per problem-pair, 25-row partition per problem:
//     lane0 obs0..5; lane1 obs6..9,slack0,box_a-; lane2 nei0..5;
//     lane3 nei6,slack1,box_a+,box_w-,box_w+,pad. conn+slack2 replicated.
// Sustained-clock note: fp32-VALU-saturated kernels run ~1.6 GHz on MI355X.

typedef float v2f __attribute__((ext_vector_type(2)));

namespace {
constexpr int N_POWER = 30;   // even
constexpr int N_FISTA = 300;  // divisible by 4 — LOCKED (r14: 200 -> 5.84 fail)
constexpr float PINV_S = 1.0f / 200.0f;  // 1/(2*W_SLACK)
constexpr float BIG = 1000.0f;

constexpr double csqrt(double x) {
    double r = x * 0.5 + 0.5;
    for (int i = 0; i < 50; ++i) r = 0.5 * (r + x / r);
    return r;
}
// beta pre-duplicated {b,b}; one scalar 32B load per 4 iterations, prefetched.
struct alignas(32) BOct { float b[8]; };
struct BetaTab8 { BOct q[N_FISTA / 4 + 1]; };  // +1 pad oct for prefetch
constexpr BetaTab8 make_beta8() {
    BetaTab8 t{};
    float tk = 1.0f;
    for (int k = 0; k < N_FISTA; ++k) {
        const float tk1 = 0.5f * (1.0f + (float)csqrt(1.0 + 4.0 * (double)tk * (double)tk));
        const float bb = (tk - 1.0f) / tk1;
        t.q[k / 4].b[(k % 4) * 2]     = bb;
        t.q[k / 4].b[(k % 4) * 2 + 1] = bb;
        tk = tk1;
    }
    return t;
}
}
__constant__ BetaTab8 BETA8 = make_beta8();

template <int CTRL>
__device__ __forceinline__ float dpp_xor_add(float x) {
    // CTRL: 0xB1 = quad_perm(1,0,3,2) = xor1 ; 0x4E = quad_perm(2,3,0,1) = xor2
    // mov_dpp + add: compiler handles DPP read-after-VALU hazards and fuses
    // via GCNDPPCombine (r10 lesson: raw asm v_add_f32_dpp skips hazard nops).
    int perm = __builtin_amdgcn_mov_dpp(__float_as_int(x), CTRL, 0xF, 0xF, true);
    return x + __int_as_float(perm);
}
__device__ __forceinline__ float dpp2(float x) {   // full quad sum
    return dpp_xor_add<0x4E>(dpp_xor_add<0xB1>(x));
}

__device__ __forceinline__ v2f vfma(v2f a, v2f b, v2f c) {
    return __builtin_elementwise_fma(a, b, c);
}
__device__ __forceinline__ v2f vmax0(v2f a) {
    const v2f z = {0.f, 0.f};
    return __builtin_elementwise_max(a, z);
}
// 6-slot packed dot product, tree-split: depth 4, two independent halves.
__device__ __forceinline__ v2f tree6(const v2f (&C)[6], const v2f (&Z)[6]) {
    v2f s0 = vfma(C[1], Z[1], C[0] * Z[0]);
    s0 = vfma(C[2], Z[2], s0);
    v2f s1 = vfma(C[4], Z[4], C[3] * Z[3]);
    s1 = vfma(C[5], Z[5], s1);
    return s0 + s1;
}

struct ConnS { float c0, c1, cB, ncb, u0, u1; };

__device__ __forceinline__ void build_scalar(
    int p, int sub,
    const float* __restrict__ u_nom, const float* __restrict__ v_cur,
    const float* __restrict__ p_obs, const float* __restrict__ obs_mask,
    const float* __restrict__ p_ag,  const float* __restrict__ v_ag,
    const float* __restrict__ ag_mask, const float* __restrict__ p_c,
    const float* __restrict__ v_c,   const float* __restrict__ c_mask,
    float (&r0)[6], float (&r1)[6], float (&rA)[6], float (&nb)[6], ConnS& cs)
{
    const float v = v_cur[p];
    cs.u0 = u_nom[2 * p];
    cs.u1 = u_nom[2 * p + 1];

#pragma unroll
    for (int s = 0; s < 6; ++s) { r0[s] = 0.f; r1[s] = 0.f; rA[s] = 0.f; nb[s] = -BIG; }

    auto obs_row = [&](int i, int s) {
        const float lx = p_obs[(p * 10 + i) * 2];
        const float ly = p_obs[(p * 10 + i) * 2 + 1];
        const float m  = obs_mask[p * 10 + i];
        const float h   = lx * lx + ly * ly - 0.25f;            // D_OBS^2
        const float hd  = -2.f * lx * v;
        const float rhs = 2.f * v * v + 3.f * hd + 2.f * h;     // DAMP=3, STIFF=2
        r0[s] = 2.f * lx * m;
        r1[s] = 2.f * ly * v * m;
        rA[s] = -m;
        nb[s] = (m > 0.f) ? -rhs : -BIG;
    };
    auto nei_row = [&](int j, int s) {
        const float ax  = p_ag[(p * 7 + j) * 2];
        const float ay  = p_ag[(p * 7 + j) * 2 + 1];
        const float vjx = v_ag[(p * 7 + j) * 2];
        const float vjy = v_ag[(p * 7 + j) * 2 + 1];
        const float m   = ag_mask[p * 7 + j];
        const float h   = ax * ax + ay * ay - 0.64f;            // D_SAFE^2
        const float hd  = -2.f * ax * v + 2.f * (ax * vjx + ay * vjy);
        const float hdd = 2.f * v * v - 2.f * v * vjx
                        + 2.f * (-v * vjx + vjx * vjx + vjy * vjy);
        const float rhs = hdd + 3.f * hd + 2.f * h;             // DAMP_A=3, STIFF_A=2
        r0[s] = 2.f * ax * m;
        r1[s] = (2.f * ay * v - 2.f * ay * vjx + 2.f * ax * vjy) * m;
        rA[s] = -m;
        nb[s] = (m > 0.f) ? -rhs : -BIG;
    };

    if (sub == 0) {
        obs_row(0, 0); obs_row(1, 1); obs_row(2, 2);
        obs_row(3, 3); obs_row(4, 4); obs_row(5, 5);
    } else if (sub == 1) {
        obs_row(6, 0); obs_row(7, 1); obs_row(8, 2); obs_row(9, 3);
        rA[4] = -1.f; nb[4] = 0.f;     // slack0: -delta_obs <= 0 (col2)
        r0[5] = -1.f; nb[5] = -2.f;    // -a <= A_MAX
    } else if (sub == 2) {
        nei_row(0, 0); nei_row(1, 1); nei_row(2, 2);
        nei_row(3, 3); nei_row(4, 4); nei_row(5, 5);
    } else {
        nei_row(6, 0);
        rA[1] = -1.f; nb[1] = 0.f;     // slack1: -delta_agent <= 0 (col3)
        r0[2] =  1.f; nb[2] = -2.f;    //  a <= A_MAX
        r1[3] = -1.f; nb[3] = -1.f;    // -w <= W_MAX
        r1[4] =  1.f; nb[4] = -1.f;    //  w <= W_MAX
        // slot5 = pad (zero coeffs, nb=-BIG): lambda provably stays 0
    }

    // conn + slack2 (col4), replicated in every lane
    {
        const float cx  = p_c[2 * p];
        const float cy  = p_c[2 * p + 1];
        const float cvx = v_c[2 * p];
        const float cvy = v_c[2 * p + 1];
        const float m   = c_mask[p];
        const float h   = 25.f - (cx * cx + cy * cy);           // D_MAX^2
        const float hd  = 2.f * cx * v - 2.f * (cx * cvx + cy * cvy);
        const float hdd = -(2.f * v * v - 2.f * v * cvx
                          + 2.f * (-v * cvx + cvx * cvx + cvy * cvy));
        const float rhs = hdd + 3.f * hd + 2.f * h;             // DAMP_CN=3, STIFF_CN=2
        cs.c0 = -2.f * cx * m;
        cs.c1 = -(2.f * cy * v - 2.f * cy * cvx + 2.f * cx * cvy) * m;
        cs.cB = -m;
        cs.ncb = (m > 0.f) ? -rhs : -BIG;
    }
}

__global__ __launch_bounds__(256, 1) void cbf_fista15(
    const float* __restrict__ u_nom,    // (B,2)
    const float* __restrict__ v_cur,    // (B,1)
    const float* __restrict__ p_obs,    // (B,10,2)
    const float* __restrict__ obs_mask, // (B,10)
    const float* __restrict__ p_ag,     // (B,7,2)
    const float* __restrict__ v_ag,     // (B,7,2)
    const float* __restrict__ ag_mask,  // (B,7)
    const float* __restrict__ p_c,      // (B,1,2)
    const float* __restrict__ v_c,      // (B,1,2)
    const float* __restrict__ c_mask,   // (B,1)
    float* __restrict__ out,            // (B,2)
    int B)
{
    const int t = blockIdx.x * 256 + threadIdx.x;
    const int q = t >> 2;        // quad index = problem-pair index
    const int sub = t & 3;
    const int half = (B + 1) >> 1;
    if (q >= half) return;       // whole quads exit together

    const int pa = q;
    const int pbi = q + half;
    const bool hasB = (pbi < B);
    const int pb = hasB ? pbi : pa;   // clamp: redundant work, store suppressed

    float r0a[6], r1a[6], rAa[6], nba[6]; ConnS ca;
    float r0b[6], r1b[6], rAb[6], nbb[6]; ConnS cb;
    build_scalar(pa, sub, u_nom, v_cur, p_obs, obs_mask, p_ag, v_ag, ag_mask, p_c, v_c, c_mask,
                 r0a, r1a, rAa, nba, ca);
    build_scalar(pb, sub, u_nom, v_cur, p_obs, obs_mask, p_ag, v_ag, ag_mask, p_c, v_c, c_mask,
                 r0b, r1b, rAb, nbb, cb);

    // pack {A,B} per slot
    v2f R0[6], R1[6], RA[6], NB[6];
#pragma unroll
    for (int k = 0; k < 6; ++k) {
        R0[k] = v2f{r0a[k], r0b[k]};
        R1[k] = v2f{r1a[k], r1b[k]};
        RA[k] = v2f{rAa[k], rAb[k]};
        NB[k] = v2f{nba[k], nbb[k]};
    }
    const v2f c0p  = {ca.c0,  cb.c0};
    const v2f c1p  = {ca.c1,  cb.c1};
    const v2f cBp  = {ca.cB,  cb.cB};
    const v2f ncbp = {ca.ncb, cb.ncb};
    const v2f u0p  = {ca.u0,  cb.u0};
    const v2f u1p  = {ca.u1,  cb.u1};

    // ---- Power iteration: L = lambda_max(A Pinv A^T), normalize every 2nd ----
    v2f PV[6];
#pragma unroll
    for (int k = 0; k < 6; ++k) PV[k] = v2f{1.f, 1.f};
    v2f pvC = {1.f, 1.f}, pvS = {1.f, 1.f};

    auto apply_M = [&]() {
        const v2f A0 = tree6(R0, PV);
        const v2f A1 = tree6(R1, PV);
        const v2f AA = tree6(RA, PV);
        const float a0A = dpp2(A0.x), a0B = dpp2(A0.y);
        const float a1A = dpp2(A1.x), a1B = dpp2(A1.y);
        const float aAA = dpp_xor_add<0xB1>(AA.x);
        const float aAB = dpp_xor_add<0xB1>(AA.y);
        const v2f a0p = vfma(c0p, pvC, v2f{a0A, a0B});
        const v2f a1p = vfma(c1p, pvC, v2f{a1A, a1B});
        const v2f aCp = vfma(cBp, pvC, -pvS);
        const v2f x0 = a0p * 0.5f, x1 = a1p * 0.5f;
        const v2f xA = v2f{aAA, aAB} * PINV_S;
        const v2f xC = aCp * PINV_S;
#pragma unroll
        for (int k = 0; k < 6; ++k)
            PV[k] = vfma(R0[k], x0, vfma(R1[k], x1, RA[k] * xA));
        pvC = vfma(c0p, x0, vfma(c1p, x1, cBp * xC));
        pvS = -xC;
    };

#pragma unroll 1
    for (int o = 0; o < N_POWER / 2; ++o) {
        apply_M();
        apply_M();
        const v2f NS = tree6(PV, PV);
        const float nA = dpp2(NS.x), nB = dpp2(NS.y);
        const v2f nsq = vfma(pvC, pvC, vfma(pvS, pvS, v2f{nA, nB}));
        const float invA = __builtin_amdgcn_rsqf(nsq.x + 1e-24f);
        const float invB = __builtin_amdgcn_rsqf(nsq.y + 1e-24f);
        const v2f INV = {invA, invB};
#pragma unroll
        for (int k = 0; k < 6; ++k) PV[k] = PV[k] * INV;
        pvC = pvC * INV;
        pvS = pvS * INV;
    }

    v2f nsh_p, pA_p;   // {-step/2}, {-step*PINV_S} per problem
    {
        const v2f A0 = tree6(R0, PV);
        const v2f A1 = tree6(R1, PV);
        const v2f AA = tree6(RA, PV);
        const float a0A = dpp2(A0.x), a0B = dpp2(A0.y);
        const float a1A = dpp2(A1.x), a1B = dpp2(A1.y);
        const float aAA = dpp_xor_add<0xB1>(AA.x);
        const float aAB = dpp_xor_add<0xB1>(AA.y);
        const v2f a0p = vfma(c0p, pvC, v2f{a0A, a0B});
        const v2f a1p = vfma(c1p, pvC, v2f{a1A, a1B});
        const v2f aCp = vfma(cBp, pvC, -pvS);
        // pair sums of slack cols: after xor1, lanes {0,1} hold col2, {2,3} col3
        const v2f aAp = {aAA, aAB};
        const v2f sq = aAp * aAp;
        const float tqA = dpp_xor_add<0x4E>(sq.x);   // col2^2 + col3^2, problem A
        const float tqB = dpp_xor_add<0x4E>(sq.y);
        const v2f tq = vfma(aCp, aCp, v2f{tqA, tqB});
        const v2f hterm = vfma(a0p, a0p, a1p * a1p) * 0.5f;
        const v2f L = vfma(tq, v2f{PINV_S, PINV_S}, hterm);
        const float stA = __builtin_amdgcn_rcpf(L.x + 1e-6f);
        const float stB = __builtin_amdgcn_rcpf(L.y + 1e-6f);
        nsh_p = v2f{stA, stB} * -0.5f;
        pA_p  = v2f{stA, stB} * -PINV_S;
    }

    // Fold pA = -step*PINV_S into the matvec-side slack coefficients once.
    v2f RA2[6];
#pragma unroll
    for (int k = 0; k < 6; ++k) RA2[k] = RA[k] * pA_p;
    const v2f cBs = cBp * pA_p;
    const v2f npA = -pA_p;
    const v2f k0p = nsh_p * c0p;   // X0 = fma(nsh, a0vec, fma(k0, zC, u0))
    const v2f k1p = nsh_p * c1p;

    // ---- FISTA on the dual, z = y/step scale, lambda ping-pong ----
    v2f ZV[6], LAE[6], LAO[6];
#pragma unroll
    for (int k = 0; k < 6; ++k) {
        ZV[k] = v2f{0.f, 0.f}; LAE[k] = v2f{0.f, 0.f}; LAO[k] = v2f{0.f, 0.f};
    }
    v2f zC = {0.f, 0.f}, zS = {0.f, 0.f};
    v2f lCE = {0.f, 0.f}, lCO = {0.f, 0.f}, lSE = {0.f, 0.f}, lSO = {0.f, 0.f};

    auto half_step = [&](v2f (&ln)[6], const v2f (&lp)[6],
                         v2f& lnC, v2f lpC, v2f& lnS, v2f lpS, v2f Bv) {
        // ---- early phase: independent of this iteration's reduces ----
        const v2f xC = vfma(cBs, zC, npA * zS);      // pA*(cB*zC - zS)
        const v2f inner0 = vfma(k0p, zC, u0p);       // nsh*c0*zC + u0
        const v2f inner1 = vfma(k1p, zC, u1p);
        v2f NBZ[6];
#pragma unroll
        for (int k = 0; k < 6; ++k) NBZ[k] = NB[k] + ZV[k];
        const v2f ncbxz = vfma(cBp, xC, ncbp + zC);  // conn: cB*xC + (-b) + z_prev
        {   // slack2 row: fully independent of the reduces
            const v2f l = vmax0(zS - xC);
            zS = vfma(Bv, l - lpS, l);
            lnS = l;
        }
        // ---- matvec + cross-lane reduce ----
        const v2f A0 = tree6(R0, ZV);
        const v2f A1 = tree6(R1, ZV);
        const v2f AA = tree6(RA2, ZV);
        const float a0A = dpp2(A0.x), a0B = dpp2(A0.y);
        const float a1A = dpp2(A1.x), a1B = dpp2(A1.y);
        const float xAA = dpp_xor_add<0xB1>(AA.x);   // == xA (pA pre-folded)
        const float xAB = dpp_xor_add<0xB1>(AA.y);
        const v2f XA = {xAA, xAB};
        const v2f X0 = vfma(nsh_p, v2f{a0A, a0B}, inner0);
        const v2f X1 = vfma(nsh_p, v2f{a1A, a1B}, inner1);
        // ---- residuals (z_prev folded into NBZ) ----
#pragma unroll
        for (int k = 0; k < 6; ++k) {
            const v2f l = vmax0(vfma(R0[k], X0, vfma(R1[k], X1, vfma(RA[k], XA, NBZ[k]))));
            ZV[k] = vfma(Bv, l - lp[k], l);
            ln[k] = l;
        }
        {   // conn row (z_prev folded into ncbxz)
            const v2f l = vmax0(vfma(c0p, X0, vfma(c1p, X1, ncbxz)));
            zC = vfma(Bv, l - lpC, l);
            lnC = l;
        }
    };

    BOct bo = BETA8.q[0];
#pragma unroll 1
    for (int o = 0; o < N_FISTA / 4; ++o) {
        const BOct bn = BETA8.q[o + 1];   // prefetch next oct (pad entry at end)
        half_step(LAE, LAO, lCE, lCO, lSE, lSO, v2f{bo.b[0], bo.b[1]});  // it=4o
        half_step(LAO, LAE, lCO, lCE, lSO, lSE, v2f{bo.b[2], bo.b[3]});  // it=4o+1
        half_step(LAE, LAO, lCE, lCO, lSE, lSO, v2f{bo.b[4], bo.b[5]});  // it=4o+2
        half_step(LAO, LAE, lCO, lCE, lSO, lSE, v2f{bo.b[6], bo.b[7]});  // it=4o+3
        bo = bn;
    }

    // ---- Final primal from lambda = step*Lambda (last write was LAO / lCO) ----
    {
        const v2f A0 = tree6(R0, LAO);
        const v2f A1 = tree6(R1, LAO);
        const float a0A = dpp2(A0.x), a0B = dpp2(A0.y);
        const float a1A = dpp2(A1.x), a1B = dpp2(A1.y);
        const v2f a0p = vfma(c0p, lCO, v2f{a0A, a0B});
        const v2f a1p = vfma(c1p, lCO, v2f{a1A, a1B});
        const v2f o0 = vfma(nsh_p, a0p, u0p);
        const v2f o1 = vfma(nsh_p, a1p, u1p);
        if (sub == 0) {
            out[2 * pa]     = o0.x;
            out[2 * pa + 1] = o1.x;
            if (hasB) {
                out[2 * pbi]     = o0.y;
                out[2 * pbi + 1] = o1.y;
            }
        }
    }
}

extern "C" void kernel_launch(void* const* d_in, const int* in_sizes, int n_in,
                              void* d_out, int out_size, void* d_ws, size_t ws_size,
                              hipStream_t stream) {
    const float* u_nom    = (const float*)d_in[0];
    const float* v_cur    = (const float*)d_in[1];
    const float* p_obs    = (const float*)d_in[2];
    const float* obs_mask = (const float*)d_in[3];
    const float* p_ag     = (const float*)d_in[4];
    const float* v_ag     = (const float*)d_in[5];
    const float* ag_mask  = (const float*)d_in[6];
    const float* p_c      = (const float*)d_in[7];
    const float* v_c      = (const float*)d_in[8];
    const float* c_mask   = (const float*)d_in[9];
    float* out = (float*)d_out;

    const int B = in_sizes[0] / 2;
    const int half = (B + 1) / 2;
    const long long threads = 4LL * half;
    const int grid = (int)((threads + 255) / 256);
    cbf_fista15<<<grid, 256, 0, stream>>>(
        u_nom, v_cur, p_obs, obs_mask, p_ag, v_ag, ag_mask, p_c, v_c, c_mask, out, B);
}

// Round 7
// 143.172 us; speedup vs baseline: 1.0413x; 1.0413x over previous
//
#include <hip/hip_runtime.h>

// Batched CBF-QP dual FISTA — r16: exact revert to r13 (best verified:
// 83.2 µs/dispatch, 144.08 µs harness).
// r15 post-mortem: manual hoist of reduce-independent ops REGRESSED
// (102.8 µs, busy 55%) — extended live ranges made the pressure-aware
// scheduler cluster dependent chains (same failure mode as r12). On this
// compiler, in-block manual scheduling is neutral-to-negative; only changes
// to the instruction stream itself (packing, constant folding) paid.
// Ceiling ledger (r0-r15):
//   - schedules: 2w ILP1 (84.4) / 1w 2-chain (99.7) / 1w packed (83.2)
//   - 8-lane repartition: instr x1.4 for 2x occupancy -> >=85 µs, ruled out
//   - N_FISTA locked at 300 (r14: 200 -> absmax 5.84 vs 0.3525 threshold)
//   - instr cuts neutral (latency-bound); memory 0.75% HBM; no spills
//
// Structure: each thread owns TWO problems (A at q, B at q+half); every v2f
// holds {A,B}, so every v_pk_fma_f32 advances both chains in lockstep
// (structural ILP — the scheduler cannot serialize it).
//   - 4 lanes/quad per problem-pair, 25-row partition per problem:
//     lane0 obs0..5; lane1 obs6..9,slack0,box_a-; lane2 nei0..5;
//     lane3 nei6,slack1,box_a+,box_w-,box_w+,pad. conn+slack2 replicated.
// Sustained-clock note: fp32-VALU-saturated kernels run ~1.6 GHz on MI355X.

typedef float v2f __attribute__((ext_vector_type(2)));

namespace {
constexpr int N_POWER = 30;   // even
constexpr int N_FISTA = 300;  // divisible by 4 — LOCKED (r14: 200 -> 5.84 fail)
constexpr float PINV_S = 1.0f / 200.0f;  // 1/(2*W_SLACK)
constexpr float BIG = 1000.0f;

constexpr double csqrt(double x) {
    double r = x * 0.5 + 0.5;
    for (int i = 0; i < 50; ++i) r = 0.5 * (r + x / r);
    return r;
}
// beta pre-duplicated {b,b}; one scalar 32B load per 4 iterations, prefetched.
struct alignas(32) BOct { float b[8]; };
struct BetaTab8 { BOct q[N_FISTA / 4 + 1]; };  // +1 pad oct for prefetch
constexpr BetaTab8 make_beta8() {
    BetaTab8 t{};
    float tk = 1.0f;
    for (int k = 0; k < N_FISTA; ++k) {
        const float tk1 = 0.5f * (1.0f + (float)csqrt(1.0 + 4.0 * (double)tk * (double)tk));
        const float bb = (tk - 1.0f) / tk1;
        t.q[k / 4].b[(k % 4) * 2]     = bb;
        t.q[k / 4].b[(k % 4) * 2 + 1] = bb;
        tk = tk1;
    }
    return t;
}
}
__constant__ BetaTab8 BETA8 = make_beta8();

template <int CTRL>
__device__ __forceinline__ float dpp_xor_add(float x) {
    // CTRL: 0xB1 = quad_perm(1,0,3,2) = xor1 ; 0x4E = quad_perm(2,3,0,1) = xor2
    // mov_dpp + add: compiler handles DPP read-after-VALU hazards and fuses
    // via GCNDPPCombine (r10 lesson: raw asm v_add_f32_dpp skips hazard nops).
    int perm = __builtin_amdgcn_mov_dpp(__float_as_int(x), CTRL, 0xF, 0xF, true);
    return x + __int_as_float(perm);
}
__device__ __forceinline__ float dpp2(float x) {   // full quad sum
    return dpp_xor_add<0x4E>(dpp_xor_add<0xB1>(x));
}

__device__ __forceinline__ v2f vfma(v2f a, v2f b, v2f c) {
    return __builtin_elementwise_fma(a, b, c);
}
__device__ __forceinline__ v2f vmax0(v2f a) {
    const v2f z = {0.f, 0.f};
    return __builtin_elementwise_max(a, z);
}
// 6-slot packed dot product, tree-split: depth 4, two independent halves.
__device__ __forceinline__ v2f tree6(const v2f (&C)[6], const v2f (&Z)[6]) {
    v2f s0 = vfma(C[1], Z[1], C[0] * Z[0]);
    s0 = vfma(C[2], Z[2], s0);
    v2f s1 = vfma(C[4], Z[4], C[3] * Z[3]);
    s1 = vfma(C[5], Z[5], s1);
    return s0 + s1;
}

struct ConnS { float c0, c1, cB, ncb, u0, u1; };

__device__ __forceinline__ void build_scalar(
    int p, int sub,
    const float* __restrict__ u_nom, const float* __restrict__ v_cur,
    const float* __restrict__ p_obs, const float* __restrict__ obs_mask,
    const float* __restrict__ p_ag,  const float* __restrict__ v_ag,
    const float* __restrict__ ag_mask, const float* __restrict__ p_c,
    const float* __restrict__ v_c,   const float* __restrict__ c_mask,
    float (&r0)[6], float (&r1)[6], float (&rA)[6], float (&nb)[6], ConnS& cs)
{
    const float v = v_cur[p];
    cs.u0 = u_nom[2 * p];
    cs.u1 = u_nom[2 * p + 1];

#pragma unroll
    for (int s = 0; s < 6; ++s) { r0[s] = 0.f; r1[s] = 0.f; rA[s] = 0.f; nb[s] = -BIG; }

    auto obs_row = [&](int i, int s) {
        const float lx = p_obs[(p * 10 + i) * 2];
        const float ly = p_obs[(p * 10 + i) * 2 + 1];
        const float m  = obs_mask[p * 10 + i];
        const float h   = lx * lx + ly * ly - 0.25f;            // D_OBS^2
        const float hd  = -2.f * lx * v;
        const float rhs = 2.f * v * v + 3.f * hd + 2.f * h;     // DAMP=3, STIFF=2
        r0[s] = 2.f * lx * m;
        r1[s] = 2.f * ly * v * m;
        rA[s] = -m;
        nb[s] = (m > 0.f) ? -rhs : -BIG;
    };
    auto nei_row = [&](int j, int s) {
        const float ax  = p_ag[(p * 7 + j) * 2];
        const float ay  = p_ag[(p * 7 + j) * 2 + 1];
        const float vjx = v_ag[(p * 7 + j) * 2];
        const float vjy = v_ag[(p * 7 + j) * 2 + 1];
        const float m   = ag_mask[p * 7 + j];
        const float h   = ax * ax + ay * ay - 0.64f;            // D_SAFE^2
        const float hd  = -2.f * ax * v + 2.f * (ax * vjx + ay * vjy);
        const float hdd = 2.f * v * v - 2.f * v * vjx
                        + 2.f * (-v * vjx + vjx * vjx + vjy * vjy);
        const float rhs = hdd + 3.f * hd + 2.f * h;             // DAMP_A=3, STIFF_A=2
        r0[s] = 2.f * ax * m;
        r1[s] = (2.f * ay * v - 2.f * ay * vjx + 2.f * ax * vjy) * m;
        rA[s] = -m;
        nb[s] = (m > 0.f) ? -rhs : -BIG;
    };

    if (sub == 0) {
        obs_row(0, 0); obs_row(1, 1); obs_row(2, 2);
        obs_row(3, 3); obs_row(4, 4); obs_row(5, 5);
    } else if (sub == 1) {
        obs_row(6, 0); obs_row(7, 1); obs_row(8, 2); obs_row(9, 3);
        rA[4] = -1.f; nb[4] = 0.f;     // slack0: -delta_obs <= 0 (col2)
        r0[5] = -1.f; nb[5] = -2.f;    // -a <= A_MAX
    } else if (sub == 2) {
        nei_row(0, 0); nei_row(1, 1); nei_row(2, 2);
        nei_row(3, 3); nei_row(4, 4); nei_row(5, 5);
    } else {
        nei_row(6, 0);
        rA[1] = -1.f; nb[1] = 0.f;     // slack1: -delta_agent <= 0 (col3)
        r0[2] =  1.f; nb[2] = -2.f;    //  a <= A_MAX
        r1[3] = -1.f; nb[3] = -1.f;    // -w <= W_MAX
        r1[4] =  1.f; nb[4] = -1.f;    //  w <= W_MAX
        // slot5 = pad (zero coeffs, nb=-BIG): lambda provably stays 0
    }

    // conn + slack2 (col4), replicated in every lane
    {
        const float cx  = p_c[2 * p];
        const float cy  = p_c[2 * p + 1];
        const float cvx = v_c[2 * p];
        const float cvy = v_c[2 * p + 1];
        const float m   = c_mask[p];
        const float h   = 25.f - (cx * cx + cy * cy);           // D_MAX^2
        const float hd  = 2.f * cx * v - 2.f * (cx * cvx + cy * cvy);
        const float hdd = -(2.f * v * v - 2.f * v * cvx
                          + 2.f * (-v * cvx + cvx * cvx + cvy * cvy));
        const float rhs = hdd + 3.f * hd + 2.f * h;             // DAMP_CN=3, STIFF_CN=2
        cs.c0 = -2.f * cx * m;
        cs.c1 = -(2.f * cy * v - 2.f * cy * cvx + 2.f * cx * cvy) * m;
        cs.cB = -m;
        cs.ncb = (m > 0.f) ? -rhs : -BIG;
    }
}

__global__ __launch_bounds__(256, 1) void cbf_fista16(
    const float* __restrict__ u_nom,    // (B,2)
    const float* __restrict__ v_cur,    // (B,1)
    const float* __restrict__ p_obs,    // (B,10,2)
    const float* __restrict__ obs_mask, // (B,10)
    const float* __restrict__ p_ag,     // (B,7,2)
    const float* __restrict__ v_ag,     // (B,7,2)
    const float* __restrict__ ag_mask,  // (B,7)
    const float* __restrict__ p_c,      // (B,1,2)
    const float* __restrict__ v_c,      // (B,1,2)
    const float* __restrict__ c_mask,   // (B,1)
    float* __restrict__ out,            // (B,2)
    int B)
{
    const int t = blockIdx.x * 256 + threadIdx.x;
    const int q = t >> 2;        // quad index = problem-pair index
    const int sub = t & 3;
    const int half = (B + 1) >> 1;
    if (q >= half) return;       // whole quads exit together

    const int pa = q;
    const int pbi = q + half;
    const bool hasB = (pbi < B);
    const int pb = hasB ? pbi : pa;   // clamp: redundant work, store suppressed

    float r0a[6], r1a[6], rAa[6], nba[6]; ConnS ca;
    float r0b[6], r1b[6], rAb[6], nbb[6]; ConnS cb;
    build_scalar(pa, sub, u_nom, v_cur, p_obs, obs_mask, p_ag, v_ag, ag_mask, p_c, v_c, c_mask,
                 r0a, r1a, rAa, nba, ca);
    build_scalar(pb, sub, u_nom, v_cur, p_obs, obs_mask, p_ag, v_ag, ag_mask, p_c, v_c, c_mask,
                 r0b, r1b, rAb, nbb, cb);

    // pack {A,B} per slot
    v2f R0[6], R1[6], RA[6], NB[6];
#pragma unroll
    for (int k = 0; k < 6; ++k) {
        R0[k] = v2f{r0a[k], r0b[k]};
        R1[k] = v2f{r1a[k], r1b[k]};
        RA[k] = v2f{rAa[k], rAb[k]};
        NB[k] = v2f{nba[k], nbb[k]};
    }
    const v2f c0p  = {ca.c0,  cb.c0};
    const v2f c1p  = {ca.c1,  cb.c1};
    const v2f cBp  = {ca.cB,  cb.cB};
    const v2f ncbp = {ca.ncb, cb.ncb};
    const v2f u0p  = {ca.u0,  cb.u0};
    const v2f u1p  = {ca.u1,  cb.u1};

    // ---- Power iteration: L = lambda_max(A Pinv A^T), normalize every 2nd ----
    v2f PV[6];
#pragma unroll
    for (int k = 0; k < 6; ++k) PV[k] = v2f{1.f, 1.f};
    v2f pvC = {1.f, 1.f}, pvS = {1.f, 1.f};

    auto apply_M = [&]() {
        const v2f A0 = tree6(R0, PV);
        const v2f A1 = tree6(R1, PV);
        const v2f AA = tree6(RA, PV);
        const float a0A = dpp2(A0.x), a0B = dpp2(A0.y);
        const float a1A = dpp2(A1.x), a1B = dpp2(A1.y);
        const float aAA = dpp_xor_add<0xB1>(AA.x);
        const float aAB = dpp_xor_add<0xB1>(AA.y);
        const v2f a0p = vfma(c0p, pvC, v2f{a0A, a0B});
        const v2f a1p = vfma(c1p, pvC, v2f{a1A, a1B});
        const v2f aCp = vfma(cBp, pvC, -pvS);
        const v2f x0 = a0p * 0.5f, x1 = a1p * 0.5f;
        const v2f xA = v2f{aAA, aAB} * PINV_S;
        const v2f xC = aCp * PINV_S;
#pragma unroll
        for (int k = 0; k < 6; ++k)
            PV[k] = vfma(R0[k], x0, vfma(R1[k], x1, RA[k] * xA));
        pvC = vfma(c0p, x0, vfma(c1p, x1, cBp * xC));
        pvS = -xC;
    };

#pragma unroll 1
    for (int o = 0; o < N_POWER / 2; ++o) {
        apply_M();
        apply_M();
        const v2f NS = tree6(PV, PV);
        const float nA = dpp2(NS.x), nB = dpp2(NS.y);
        const v2f nsq = vfma(pvC, pvC, vfma(pvS, pvS, v2f{nA, nB}));
        const float invA = __builtin_amdgcn_rsqf(nsq.x + 1e-24f);
        const float invB = __builtin_amdgcn_rsqf(nsq.y + 1e-24f);
        const v2f INV = {invA, invB};
#pragma unroll
        for (int k = 0; k < 6; ++k) PV[k] = PV[k] * INV;
        pvC = pvC * INV;
        pvS = pvS * INV;
    }

    v2f nsh_p, pA_p;   // {-step/2}, {-step*PINV_S} per problem
    {
        const v2f A0 = tree6(R0, PV);
        const v2f A1 = tree6(R1, PV);
        const v2f AA = tree6(RA, PV);
        const float a0A = dpp2(A0.x), a0B = dpp2(A0.y);
        const float a1A = dpp2(A1.x), a1B = dpp2(A1.y);
        const float aAA = dpp_xor_add<0xB1>(AA.x);
        const float aAB = dpp_xor_add<0xB1>(AA.y);
        const v2f a0p = vfma(c0p, pvC, v2f{a0A, a0B});
        const v2f a1p = vfma(c1p, pvC, v2f{a1A, a1B});
        const v2f aCp = vfma(cBp, pvC, -pvS);
        // pair sums of slack cols: after xor1, lanes {0,1} hold col2, {2,3} col3
        const v2f aAp = {aAA, aAB};
        const v2f sq = aAp * aAp;
        const float tqA = dpp_xor_add<0x4E>(sq.x);   // col2^2 + col3^2, problem A
        const float tqB = dpp_xor_add<0x4E>(sq.y);
        const v2f tq = vfma(aCp, aCp, v2f{tqA, tqB});
        const v2f hterm = vfma(a0p, a0p, a1p * a1p) * 0.5f;
        const v2f L = vfma(tq, v2f{PINV_S, PINV_S}, hterm);
        const float stA = __builtin_amdgcn_rcpf(L.x + 1e-6f);
        const float stB = __builtin_amdgcn_rcpf(L.y + 1e-6f);
        nsh_p = v2f{stA, stB} * -0.5f;
        pA_p  = v2f{stA, stB} * -PINV_S;
    }

    // Fold pA = -step*PINV_S into the matvec-side slack coefficients once.
    v2f RA2[6];
#pragma unroll
    for (int k = 0; k < 6; ++k) RA2[k] = RA[k] * pA_p;
    const v2f cBs = cBp * pA_p;
    const v2f npA = -pA_p;

    // ---- FISTA on the dual, z = y/step scale, lambda ping-pong ----
    v2f ZV[6], LAE[6], LAO[6];
#pragma unroll
    for (int k = 0; k < 6; ++k) {
        ZV[k] = v2f{0.f, 0.f}; LAE[k] = v2f{0.f, 0.f}; LAO[k] = v2f{0.f, 0.f};
    }
    v2f zC = {0.f, 0.f}, zS = {0.f, 0.f};
    v2f lCE = {0.f, 0.f}, lCO = {0.f, 0.f}, lSE = {0.f, 0.f}, lSO = {0.f, 0.f};

    auto half_step = [&](v2f (&ln)[6], const v2f (&lp)[6],
                         v2f& lnC, v2f lpC, v2f& lnS, v2f lpS, v2f Bv) {
        const v2f A0 = tree6(R0, ZV);
        const v2f A1 = tree6(R1, ZV);
        const v2f AA = tree6(RA2, ZV);
        const float a0A = dpp2(A0.x), a0B = dpp2(A0.y);
        const float a1A = dpp2(A1.x), a1B = dpp2(A1.y);
        const float xAA = dpp_xor_add<0xB1>(AA.x);   // == xA (pA pre-folded)
        const float xAB = dpp_xor_add<0xB1>(AA.y);
        const v2f XA = {xAA, xAB};
        const v2f xC = vfma(cBs, zC, npA * zS);      // pA*(cB*zC - zS)
        const v2f X0 = vfma(nsh_p, vfma(c0p, zC, v2f{a0A, a0B}), u0p);
        const v2f X1 = vfma(nsh_p, vfma(c1p, zC, v2f{a1A, a1B}), u1p);
#pragma unroll
        for (int k = 0; k < 6; ++k) {
            const v2f resid = vfma(R0[k], X0, vfma(R1[k], X1, vfma(RA[k], XA, NB[k])));
            const v2f l = vmax0(ZV[k] + resid);
            ZV[k] = vfma(Bv, l - lp[k], l);
            ln[k] = l;
        }
        {   // conn row, both problems packed
            const v2f residC = vfma(c0p, X0, vfma(c1p, X1, vfma(cBp, xC, ncbp)));
            const v2f l = vmax0(zC + residC);
            zC = vfma(Bv, l - lpC, l);
            lnC = l;
        }
        {   // slack2 row: resid = -xC
            const v2f l = vmax0(zS - xC);
            zS = vfma(Bv, l - lpS, l);
            lnS = l;
        }
    };

    BOct bo = BETA8.q[0];
#pragma unroll 1
    for (int o = 0; o < N_FISTA / 4; ++o) {
        const BOct bn = BETA8.q[o + 1];   // prefetch next oct (pad entry at end)
        half_step(LAE, LAO, lCE, lCO, lSE, lSO, v2f{bo.b[0], bo.b[1]});  // it=4o
        half_step(LAO, LAE, lCO, lCE, lSO, lSE, v2f{bo.b[2], bo.b[3]});  // it=4o+1
        half_step(LAE, LAO, lCE, lCO, lSE, lSO, v2f{bo.b[4], bo.b[5]});  // it=4o+2
        half_step(LAO, LAE, lCO, lCE, lSO, lSE, v2f{bo.b[6], bo.b[7]});  // it=4o+3
        bo = bn;
    }

    // ---- Final primal from lambda = step*Lambda (last write was LAO / lCO) ----
    {
        const v2f A0 = tree6(R0, LAO);
        const v2f A1 = tree6(R1, LAO);
        const float a0A = dpp2(A0.x), a0B = dpp2(A0.y);
        const float a1A = dpp2(A1.x), a1B = dpp2(A1.y);
        const v2f a0p = vfma(c0p, lCO, v2f{a0A, a0B});
        const v2f a1p = vfma(c1p, lCO, v2f{a1A, a1B});
        const v2f o0 = vfma(nsh_p, a0p, u0p);
        const v2f o1 = vfma(nsh_p, a1p, u1p);
        if (sub == 0) {
            out[2 * pa]     = o0.x;
            out[2 * pa + 1] = o1.x;
            if (hasB) {
                out[2 * pbi]     = o0.y;
                out[2 * pbi + 1] = o1.y;
            }
        }
    }
}

extern "C" void kernel_launch(void* const* d_in, const int* in_sizes, int n_in,
                              void* d_out, int out_size, void* d_ws, size_t ws_size,
                              hipStream_t stream) {
    const float* u_nom    = (const float*)d_in[0];
    const float* v_cur    = (const float*)d_in[1];
    const float* p_obs    = (const float*)d_in[2];
    const float* obs_mask = (const float*)d_in[3];
    const float* p_ag     = (const float*)d_in[4];
    const float* v_ag     = (const float*)d_in[5];
    const float* ag_mask  = (const float*)d_in[6];
    const float* p_c      = (const float*)d_in[7];
    const float* v_c      = (const float*)d_in[8];
    const float* c_mask   = (const float*)d_in[9];
    float* out = (float*)d_out;

    const int B = in_sizes[0] / 2;
    const int half = (B + 1) / 2;
    const long long threads = 4LL * half;
    const int grid = (int)((threads + 255) / 256);
    cbf_fista16<<<grid, 256, 0, stream>>>(
        u_nom, v_cur, p_obs, obs_mask, p_ag, v_ag, ag_mask, p_c, v_c, c_mask, out, B);
}